// Round 13
// baseline (1279.675 us; speedup 1.0000x reference)
//
#include <hip/hip_runtime.h>
#include <cstdint>
#include <cstddef>

// ConvGRU autoencoder, round 13: r12 + merged windows (3 barriers/t, was 4).
// New 32-cb map with dedicated dead-zero pads so e1B(t-1)+postB can share a
// window with e0A(t)+postA (and d1B/d0A likewise):
//  enc: cb0 x, cb1-4 h0, cb5-7 DEAD, cb8-15 h1, cb16 x-dup, cb17-20 rh0,
//       cb21-23 DEAD, cb24-31 rh1
//  dec: cb0-7 y1, cb8-15 hd0, cb16-19 hd1, cb20-27 rh_d0, cb28-31 rh_d1
// Windows/t:  M[prevB+postB || curA+postA] | W3[e0B/d0B(+out/x-issue)] |
//             W4[e1A/d1A(+ingest write)] |
// Hazards verified per window (all cb-disjoint; dead cbs never written).
// wcD1 streamed from global to fit dec LDS weights in 86016 B.

#define F_ 128
#define T_ 100
#define B_ 64
#define ROWSP 130
#define CBSTR (ROWSP * 8)    // f16 per cb
#define CBBYTE (ROWSP * 16)  // bytes per cb
#define AT_OFF 86016
#define NCB 32
#define LDS_TOTAL (AT_OFF + NCB * CBBYTE)  // 86016 + 66560 = 152576

typedef _Float16 f16;
typedef __attribute__((ext_vector_type(4))) float f32x4;
typedef __attribute__((ext_vector_type(8))) _Float16 f16x8;
typedef __attribute__((ext_vector_type(4))) _Float16 f16x4;

#define MFMA(a, b, c) __builtin_amdgcn_mfma_f32_16x16x32_f16(a, b, c, 0, 0, 0)

__device__ __forceinline__ float exp2_(float x) { return __builtin_amdgcn_exp2f(x); }
__device__ __forceinline__ float rcp_(float x) { return __builtin_amdgcn_rcpf(x); }

#define KSG (-1.442695041f)  // sigmoid: sig(v) = rcp(1+exp2(v*KSG))
#define KTH (-2.885390082f)  // tanh:    tanh(v) = 2*rcp(1+exp2(v*KTH)) - 1

// cb base per (layer, ks%NC3); fragment cb = base + kb (kb = lane>>4).
__host__ __device__ constexpr int cbA(int lid, int km) {
  return lid == 0 ? (km ? 4 : 0)
       : lid == 1 ? (km == 0 ? 1 : 4 + 4 * km)
       : lid == 2 ? (4 * km)
                  : (8 + 4 * km);
}
__host__ __device__ constexpr int cbB(int lid, int km) {
  return lid == 0 ? (km ? 20 : 16)
       : lid == 1 ? (km == 0 ? 1 : 20 + 4 * km)
       : lid == 2 ? (km < 2 ? 4 * km : 12 + 4 * km)
                  : (km < 2 ? 8 + 4 * km : 28);
}

// Gate convs (R,U) over [x ; h]. Weights from regs (WREG) or LDS.
template <int LID, int FTW, int NK, int NC3, bool WREG>
__device__ __forceinline__ void convA_f(
    const f16* __restrict__ rdB,
    const f16x8* __restrict__ aR, const f16x8* __restrict__ aU,
    const f16* __restrict__ gR, const f16* __restrict__ gU,
    f32x4* __restrict__ accR, f32x4* __restrict__ accU) {
#pragma unroll
  for (int j = 0; j < FTW; ++j) {
    accR[j] = (f32x4){0.f, 0.f, 0.f, 0.f};
    accU[j] = (f32x4){0.f, 0.f, 0.f, 0.f};
  }
#pragma unroll
  for (int ks = 0; ks < NK; ++ks) {
    const int k = ks / NC3, km = ks % NC3;
    const f16* fb = rdB + cbA(LID, km) * CBSTR + k * 8;
    f16x8 bf[FTW];
#pragma unroll
    for (int j = 0; j < FTW; ++j) bf[j] = *(const f16x8*)(fb + j * 128);
    f16x8 wr, wu;
    if constexpr (WREG) { wr = aR[ks]; wu = aU[ks]; }
    else {
      wr = *(const f16x8*)(gR + ks * 512);
      wu = *(const f16x8*)(gU + ks * 512);
    }
#pragma unroll
    for (int j = 0; j < FTW; ++j) accR[j] = MFMA(wr, bf[j], accR[j]);
#pragma unroll
    for (int j = 0; j < FTW; ++j) accU[j] = MFMA(wu, bf[j], accU[j]);
  }
}

// Candidate conv over [x ; r*h]. Weights from regs (CREG) or LDS.
template <int LID, int FTW, int NK, int NC3, bool CREG>
__device__ __forceinline__ void convB_f(
    const f16* __restrict__ rdB, const f16x8* __restrict__ cR,
    const f16* __restrict__ cW, f32x4* __restrict__ accC) {
#pragma unroll
  for (int j = 0; j < FTW; ++j) accC[j] = (f32x4){0.f, 0.f, 0.f, 0.f};
#pragma unroll
  for (int ks = 0; ks < NK; ++ks) {
    const int k = ks / NC3, km = ks % NC3;
    const f16* fb = rdB + cbB(LID, km) * CBSTR + k * 8;
    f16x8 bf[FTW];
#pragma unroll
    for (int j = 0; j < FTW; ++j) bf[j] = *(const f16x8*)(fb + j * 128);
    f16x8 wc;
    if constexpr (CREG) wc = cR[ks];
    else wc = *(const f16x8*)(cW + ks * 512);
#pragma unroll
    for (int j = 0; j < FTW; ++j) accC[j] = MFMA(wc, bf[j], accC[j]);
  }
}

// rh = sigm(R)*h into cb RHCB (relative to wrB's base cb).
template <int FTW, int RHCB>
__device__ __forceinline__ void postA_f(const f32x4* __restrict__ accR,
                                        const f32x4 bR,
                                        const f32x4* __restrict__ hreg,
                                        char* __restrict__ wrB) {
#pragma unroll
  for (int j = 0; j < FTW; ++j) {
    f16x4 rh;
#pragma unroll
    for (int q = 0; q < 4; ++q) {
      const float r = rcp_(1.0f + exp2_(fmaf(accR[j][q], KSG, bR[q])));
      rh[q] = (f16)(r * hreg[j][q]);
    }
    *(f16x4*)(wrB + RHCB * CBBYTE + j * 256) = rh;
  }
}

// u = sigm(U); h = h + u*(tanh(C)-h); write h cb (+ y1 emit).
template <int FTW, int HCB, bool EMITY1>
__device__ __forceinline__ void postB_f(const f32x4* __restrict__ accU,
                                        const f32x4* __restrict__ accC,
                                        const f32x4 bU, const f32x4 bC,
                                        f32x4* __restrict__ hreg,
                                        char* __restrict__ wrB,
                                        f16* __restrict__ y1dst) {
#pragma unroll
  for (int j = 0; j < FTW; ++j) {
    f16x4 hh;
#pragma unroll
    for (int q = 0; q < 4; ++q) {
      const float u = rcp_(1.0f + exp2_(fmaf(accU[j][q], KSG, bU[q])));
      const float r = rcp_(1.0f + exp2_(fmaf(accC[j][q], KTH, bC[q])));
      const float h = hreg[j][q];
      const float s = fmaf(2.0f, r, -(1.0f + h));  // tanh(C) - h
      const float hn = fmaf(u, s, h);
      hreg[j][q] = hn;
      hh[q] = (f16)hn;
    }
    *(f16x4*)(wrB + HCB * CBBYTE + j * 256) = hh;
    if constexpr (EMITY1) *(f16x4*)(y1dst + j * 128) = hh;
  }
}

__global__ __launch_bounds__(512, 1) void ae_kernel(
    const f16* __restrict__ xf, float* __restrict__ out,
    const f16* __restrict__ wgE0, const f16* __restrict__ wcE0,
    const float* __restrict__ bgE0, const float* __restrict__ bcE0,
    const f16* __restrict__ wgE1, const f16* __restrict__ wcE1,
    const float* __restrict__ bgE1, const float* __restrict__ bcE1,
    const f16* __restrict__ wgD0, const f16* __restrict__ wcD0,
    const float* __restrict__ bgD0, const float* __restrict__ bcD0,
    const f16* __restrict__ wgD1, const f16* __restrict__ wcD1,
    const float* __restrict__ bgD1, const float* __restrict__ bcD1,
    const float* __restrict__ fw, const float* __restrict__ fb,
    f16* __restrict__ y1g) {
  extern __shared__ char smem[];
  f16* aT = (f16*)(smem + AT_OFF);
  const int tid = threadIdx.x, b = blockIdx.x;
  const int w = tid >> 6, l = tid & 63;
  const int m16 = l & 15, kb = l >> 4;

  // zero aT (32 cb; dead cbs 5-7 & 21-23 stay zero forever)
  for (int i = tid; i < NCB * CBBYTE / 16; i += 512)
    ((f32x4*)(smem + AT_OFF))[i] = (f32x4){0.f, 0.f, 0.f, 0.f};
  // encoder LDS weights: wgE0@0 (24576 B), wcE0@24576 (12288 B)
  for (int i = tid; i < 1536; i += 512)
    ((f16x8*)(smem + 0))[i] = ((const f16x8*)wgE0)[i];
  for (int i = tid; i < 768; i += 512)
    ((f16x8*)(smem + 24576))[i] = ((const f16x8*)wcE0)[i];

  // e1 gate + cand weights (compiler streams from L2; r9-proven placement)
  const int cot2 = w & 1, cot4 = w & 3;
  f16x8 aR1[9], aU1[9], cE1[9];
#pragma unroll
  for (int ks = 0; ks < 9; ++ks) {
    aR1[ks] = ((const f16x8*)wgE1)[(cot4 * 9 + ks) * 64 + l];
    aU1[ks] = ((const f16x8*)wgE1)[((cot4 + 4) * 9 + ks) * 64 + l];
    cE1[ks] = ((const f16x8*)wcE1)[(cot4 * 9 + ks) * 64 + l];
  }
  // enc biases (scale folded)
  const int co2 = cot2 * 16 + kb * 4;
  const int co4 = cot4 * 16 + kb * 4;
  f32x4 bRe0, bUe0, bCe0, bRe1, bUe1, bCe1;
#pragma unroll
  for (int q = 0; q < 4; ++q) {
    bRe0[q] = bgE0[co2 + q] * KSG;
    bUe0[q] = bgE0[32 + co2 + q] * KSG;
    bCe0[q] = bcE0[co2 + q] * KTH;
    bRe1[q] = bgE1[co4 + q] * KSG;
    bUe1[q] = bgE1[64 + co4 + q] * KSG;
    bCe1[q] = bcE1[co4 + q] * KTH;
  }
  // per-thread LDS bases
  const int ft2 = (w >> 1) * 2, ft4 = (w >> 2) * 4;
  const f16* rdB2 = aT + kb * CBSTR + (ft2 * 16 + m16) * 8;
  const f16* rdB4 = aT + kb * CBSTR + (ft4 * 16 + m16) * 8;
  char* wrB2 = (char*)aT + (cot2 * 2 + (kb >> 1)) * CBBYTE +
               (ft2 * 16 + m16 + 1) * 16 + (kb & 1) * 8;
  char* wrB4 = (char*)aT + (cot4 * 2 + (kb >> 1)) * CBBYTE +
               (ft4 * 16 + m16 + 1) * 16 + (kb & 1) * 8;
  f16* y1t = y1g + (size_t)b * T_ * 8192 +
             ((cot4 * 2 + (kb >> 1)) * 128 + ft4 * 16 + m16) * 8 + (kb & 1) * 4;
  const f16* gE0R = (const f16*)(smem + 0) + (cot2 * 6) * 512 + l * 8;
  const f16* gE0U = (const f16*)(smem + 0) + ((2 + cot2) * 6) * 512 + l * 8;
  const f16* cE0l = (const f16*)(smem + 24576) + (cot2 * 6) * 512 + l * 8;

  f32x4 h0r[2], h1r[4];
#pragma unroll
  for (int j = 0; j < 2; ++j) h0r[j] = (f32x4){0.f, 0.f, 0.f, 0.f};
#pragma unroll
  for (int j = 0; j < 4; ++j) h1r[j] = (f32x4){0.f, 0.f, 0.f, 0.f};
  __syncthreads();

  // ================= encoder (3 barriers/t) =================
  const f16* xb = xf + (size_t)b * T_ * F_;
  if (tid < F_) {  // ingest x(0) -> cb0 and cb16 (x-dup)
    const f16 v = xb[tid];
    aT[(tid + 1) * 8] = v;
    aT[16 * CBSTR + (tid + 1) * 8] = v;
  }
  __syncthreads();
  f32x4 aU1g[4], aR1g[4];
  for (int t = 0; t < T_; ++t) {
    // M: e1B(t-1)+postB  ||  e0A(t)+postA
    f32x4 aC1[4], aR0g[2], aU0g[2];
    if (t > 0) convB_f<1, 4, 9, 3, true>(rdB4, cE1, nullptr, aC1);
    convA_f<0, 2, 6, 2, false>(rdB2, nullptr, nullptr, gE0R, gE0U, aR0g, aU0g);
    if (t > 0)
      postB_f<4, 8, true>(aU1g, aC1, bUe1, bCe1, h1r, wrB4,
                          y1t + (size_t)(t - 1) * 8192);
    postA_f<2, 17>(aR0g, bRe0, h0r, wrB2);
    __syncthreads();
    // W3: e0B + postB ; issue x(t+1) -> reg
    f32x4 aC0[2];
    convB_f<0, 2, 6, 2, false>(rdB2, nullptr, cE0l, aC0);
    f16 xpre = (f16)0.f;
    if (t + 1 < T_ && tid < F_) xpre = xb[(t + 1) * F_ + tid];
    postB_f<2, 1, false>(aU0g, aC0, bUe0, bCe0, h0r, wrB2, nullptr);
    __syncthreads();
    // W4: e1A(t) + postA ; write x(t+1) (cb0/cb16 not read here)
    convA_f<1, 4, 9, 3, true>(rdB4, aR1, aU1, nullptr, nullptr, aR1g, aU1g);
    if (t + 1 < T_ && tid < F_) {
      aT[(tid + 1) * 8] = xpre;
      aT[16 * CBSTR + (tid + 1) * 8] = xpre;
    }
    postA_f<4, 24>(aR1g, bRe1, h1r, wrB4);
    __syncthreads();
  }
  {  // epilogue: e1B(T-1)+postB (h1 -> cb8-15 = hd0 init); hd1 init -> cb16-19
    f32x4 aC1[4];
    convB_f<1, 4, 9, 3, true>(rdB4, cE1, nullptr, aC1);
    postB_f<4, 8, true>(aU1g, aC1, bUe1, bCe1, h1r, wrB4,
                        y1t + (size_t)(T_ - 1) * 8192);
#pragma unroll
    for (int j = 0; j < 2; ++j) {
      f16x4 hh;
#pragma unroll
      for (int q = 0; q < 4; ++q) hh[q] = (f16)h0r[j][q];
      *(f16x4*)(wrB2 + 16 * CBBYTE + j * 256) = hh;
    }
  }
  __syncthreads();

  // ======== transition: dec LDS weights (exactly fill [0, 86016)) ========
  for (int i = tid; i < 3072; i += 512)
    ((f16x8*)(smem + 0))[i] = ((const f16x8*)wcD0)[i];
  for (int i = tid; i < 2304; i += 512)
    ((f16x8*)(smem + 49152))[i] = ((const f16x8*)wgD1)[i];
  // d0 gates + d1 cand (compiler streams from L2)
  f16x8 aR0[12], aU0[12], wCd1[9];
#pragma unroll
  for (int ks = 0; ks < 12; ++ks) {
    aR0[ks] = ((const f16x8*)wgD0)[(cot4 * 12 + ks) * 64 + l];
    aU0[ks] = ((const f16x8*)wgD0)[((cot4 + 4) * 12 + ks) * 64 + l];
  }
#pragma unroll
  for (int ks = 0; ks < 9; ++ks)
    wCd1[ks] = ((const f16x8*)wcD1)[(cot2 * 9 + ks) * 64 + l];
  // dec biases
  f32x4 bRd0, bUd0, bCd0, bRd1, bUd1, bCd1;
#pragma unroll
  for (int q = 0; q < 4; ++q) {
    bRd0[q] = bgD0[co4 + q] * KSG;
    bUd0[q] = bgD0[64 + co4 + q] * KSG;
    bCd0[q] = bcD0[co4 + q] * KTH;
    bRd1[q] = bgD1[co2 + q] * KSG;
    bUd1[q] = bgD1[32 + co2 + q] * KSG;
    bCd1[q] = bcD1[co2 + q] * KTH;
  }
  const f16* gD1R = (const f16*)(smem + 49152) + (cot2 * 9) * 512 + l * 8;
  const f16* gD1U = (const f16*)(smem + 49152) + ((2 + cot2) * 9) * 512 + l * 8;
  const f16* cD0l = (const f16*)(smem + 0) + (cot4 * 12) * 512 + l * 8;
  const float fb0 = fb[0];
  __syncthreads();
  {  // ingest y1(0) -> cb0-7
    const f16x8* src = (const f16x8*)(y1g + (size_t)b * T_ * 8192);
#pragma unroll
    for (int k2 = 0; k2 < 2; ++k2) {
      const int i = tid + k2 * 512;
      *(f16x8*)&aT[(i >> 7) * CBSTR + ((i & 127) + 1) * 8] = src[i];
    }
  }
  __syncthreads();

  // ================= decoder (3 barriers/t; out in W3) =================
  f32x4 aUd1[2], aRd1[2];
  for (int t = 0; t < T_; ++t) {
    // M: d1B(t-1)+postB || d0A(t)+postA ; issue y1(t+1) -> reg
    f32x4 aCd1[2], aRd0[4], aUd0[4];
    if (t > 0) convB_f<3, 2, 9, 3, true>(rdB2, wCd1, nullptr, aCd1);
    convA_f<2, 4, 12, 4, true>(rdB4, aR0, aU0, nullptr, nullptr, aRd0, aUd0);
    f16x8 yp0 = {}, yp1 = {};
    if (t + 1 < T_) {
      const f16x8* src = (const f16x8*)(y1g + ((size_t)b * T_ + t + 1) * 8192);
      yp0 = src[tid];
      yp1 = src[tid + 512];
    }
    if (t > 0) postB_f<2, 16, false>(aUd1, aCd1, bUd1, bCd1, h0r, wrB2, nullptr);
    postA_f<4, 20>(aRd0, bRd0, h1r, wrB4);
    __syncthreads();
    // W3: d0B + postB ; out(t-1) (cb16-19 written in M, barrier-separated)
    f32x4 aCd0[4];
    convB_f<2, 4, 12, 4, false>(rdB4, nullptr, cD0l, aCd0);
    if (t >= 1 && tid < F_) {
      float s = fb0;
#pragma unroll
      for (int cb = 0; cb < 4; ++cb) {
        const f16x8 h8 = *(const f16x8*)&aT[(16 + cb) * CBSTR + (tid + 1) * 8];
#pragma unroll
        for (int q = 0; q < 8; ++q) s = fmaf(fw[cb * 8 + q], (float)h8[q], s);
      }
      out[((size_t)b * T_ + (t - 1)) * F_ + tid] = s;
    }
    postB_f<4, 8, false>(aUd0, aCd0, bUd0, bCd0, h1r, wrB4, nullptr);
    __syncthreads();
    // W4: d1A(t)+postA ; write y1(t+1) -> cb0-7 (not read here)
    convA_f<3, 2, 9, 3, false>(rdB2, nullptr, nullptr, gD1R, gD1U, aRd1, aUd1);
    if (t + 1 < T_) {
      const int i0 = tid, i1 = tid + 512;
      *(f16x8*)&aT[(i0 >> 7) * CBSTR + ((i0 & 127) + 1) * 8] = yp0;
      *(f16x8*)&aT[(i1 >> 7) * CBSTR + ((i1 & 127) + 1) * 8] = yp1;
    }
    postA_f<2, 28>(aRd1, bRd1, h0r, wrB2);
    __syncthreads();
  }
  {  // epilogue: d1B(T-1)+postB, then out(T-1)
    f32x4 aCd1[2];
    convB_f<3, 2, 9, 3, true>(rdB2, wCd1, nullptr, aCd1);
    postB_f<2, 16, false>(aUd1, aCd1, bUd1, bCd1, h0r, wrB2, nullptr);
  }
  __syncthreads();
  if (tid < F_) {
    float s = fb0;
#pragma unroll
    for (int cb = 0; cb < 4; ++cb) {
      const f16x8 h8 = *(const f16x8*)&aT[(16 + cb) * CBSTR + (tid + 1) * 8];
#pragma unroll
      for (int q = 0; q < 8; ++q) s = fmaf(fw[cb * 8 + q], (float)h8[q], s);
    }
    out[((size_t)b * T_ + (T_ - 1)) * F_ + tid] = s;
  }
}

// (CO,CI,3,3) fp32 -> f16 packed per MFMA A-fragment:
// dst[((cot*NK+ks)*64+lane)*8+j] = W[cot*16+(lane&15)][kk=ks*32+(lane>>4)*8+j]
__global__ void repack_f16(const float* __restrict__ src, f16* __restrict__ dst,
                           int CO, int CI, int CINH, int NK, int e0map) {
  const int n = (CO / 16) * NK * 64;
  for (int i = blockIdx.x * blockDim.x + threadIdx.x; i < n;
       i += gridDim.x * blockDim.x) {
    const int cot = i / (NK * 64);
    const int r = i - cot * NK * 64;
    const int ks = r >> 6, lph = r & 63;
    const int co = cot * 16 + (lph & 15);
    const int kbl = lph >> 4;
#pragma unroll
    for (int j = 0; j < 8; ++j) {
      const int kk = ks * 32 + kbl * 8 + j;
      const int k = kk / CINH, c = kk - k * CINH;
      int ci;
      if (e0map) ci = (c == 0) ? 0 : ((c >= 8 && c < 40) ? c - 7 : -1);
      else ci = (c < CI) ? c : -1;
      float wv = 0.f;
      if (ci >= 0) wv = src[((size_t)(co * CI + ci) * 3 + k) * 3 + 1];
      dst[(size_t)i * 8 + j] = (f16)wv;
    }
  }
}

__global__ void xcvt(const float* __restrict__ x, f16* __restrict__ xf, int n4) {
  for (int i = blockIdx.x * blockDim.x + threadIdx.x; i < n4;
       i += gridDim.x * blockDim.x) {
    const float4 v = ((const float4*)x)[i];
    f16x4 o;
    o[0] = (f16)v.x; o[1] = (f16)v.y; o[2] = (f16)v.z; o[3] = (f16)v.w;
    ((f16x4*)xf)[i] = o;
  }
}

extern "C" void kernel_launch(void* const* d_in, const int* in_sizes, int n_in,
                              void* d_out, int out_size, void* d_ws, size_t ws_size,
                              hipStream_t stream) {
  (void)in_sizes; (void)n_in; (void)out_size; (void)ws_size;
  const float* x = (const float*)d_in[0];
  const float* e0_wg = (const float*)d_in[1];
  const float* e0_bg = (const float*)d_in[2];
  const float* e0_wc = (const float*)d_in[3];
  const float* e0_bc = (const float*)d_in[4];
  const float* e1_wg = (const float*)d_in[5];
  const float* e1_bg = (const float*)d_in[6];
  const float* e1_wc = (const float*)d_in[7];
  const float* e1_bc = (const float*)d_in[8];
  const float* d0_wg = (const float*)d_in[9];
  const float* d0_bg = (const float*)d_in[10];
  const float* d0_wc = (const float*)d_in[11];
  const float* d0_bc = (const float*)d_in[12];
  const float* d1_wg = (const float*)d_in[13];
  const float* d1_bg = (const float*)d_in[14];
  const float* d1_wc = (const float*)d_in[15];
  const float* d1_bc = (const float*)d_in[16];
  const float* fw = (const float*)d_in[17];
  const float* fb = (const float*)d_in[18];
  float* out = (float*)d_out;

  char* p = (char*)d_ws;
  f16* y1g = (f16*)p;
  p += (size_t)B_ * T_ * 64 * 128 * 2;  // 104.86 MB
  f16* xf = (f16*)p;
  p += (size_t)B_ * T_ * F_ * 2;        // 1.64 MB
  auto aw = [&](int n) { f16* q = (f16*)p; p += (size_t)n * 2; return q; };
  f16* wgE0 = aw(64 * 192);
  f16* wcE0 = aw(32 * 192);
  f16* wgE1 = aw(128 * 288);
  f16* wcE1 = aw(64 * 288);
  f16* wgD0 = aw(128 * 384);
  f16* wcD0 = aw(64 * 384);
  f16* wgD1 = aw(64 * 288);
  f16* wcD1 = aw(32 * 288);

  auto rp = [&](const float* s, f16* d, int CO, int CI, int CINH, int e0m) {
    const int NK = 3 * CINH / 32;
    const int n = (CO / 16) * NK * 64;
    hipLaunchKernelGGL(repack_f16, dim3((n + 255) / 256), dim3(256), 0, stream,
                       s, d, CO, CI, CINH, NK, e0m);
  };
  rp(e0_wg, wgE0, 64, 33, 64, 1);
  rp(e0_wc, wcE0, 32, 33, 64, 1);
  rp(e1_wg, wgE1, 128, 96, 96, 0);
  rp(e1_wc, wcE1, 64, 96, 96, 0);
  rp(d0_wg, wgD0, 128, 128, 128, 0);
  rp(d0_wc, wcD0, 64, 128, 128, 0);
  rp(d1_wg, wgD1, 64, 96, 96, 0);
  rp(d1_wc, wcD1, 32, 96, 96, 0);
  hipLaunchKernelGGL(xcvt, dim3(200), dim3(1024), 0, stream, x, xf,
                     B_ * T_ * F_ / 4);

  hipFuncSetAttribute((const void*)ae_kernel,
                      hipFuncAttributeMaxDynamicSharedMemorySize, LDS_TOTAL);
  hipLaunchKernelGGL(ae_kernel, dim3(B_), dim3(512), LDS_TOTAL, stream, xf, out,
                     wgE0, wcE0, e0_bg, e0_bc, wgE1, wcE1, e1_bg, e1_bc,
                     wgD0, wcD0, d0_bg, d0_bc, wgD1, wcD1, d1_bg, d1_bc,
                     fw, fb, y1g);
}